// Round 13
// baseline (181.629 us; speedup 1.0000x reference)
//
#include <hip/hip_runtime.h>

typedef _Float16 half8 __attribute__((ext_vector_type(8)));
typedef float f32x4 __attribute__((ext_vector_type(4)));

#define IN_F 4096
#define OUT_F 4096
#define RANK 64
#define M_TOT 8192
#define KCHUNK 1024
#define NKC (IN_F / KCHUNK)
#define NBLK (M_TOT / 16)   // 512

// 2 aligned groups of 4: 2:4 soft-threshold, scale, cast f16. VALIDATED (r4/r5).
__device__ __forceinline__ half8 thresh8(const float* __restrict__ p, float scale) {
    half8 h;
    #pragma unroll
    for (int g = 0; g < 2; ++g) {
        f32x4 v = *(const f32x4*)(p + 4 * g);
        float m0 = fabsf(v[0]), m1 = fabsf(v[1]), m2 = fabsf(v[2]), m3 = fabsf(v[3]);
        float lo1 = fminf(m0, m1), hi1 = fmaxf(m0, m1);
        float lo2 = fminf(m2, m3), hi2 = fmaxf(m2, m3);
        float t = fminf(fmaxf(lo1, lo2), fminf(hi1, hi2));
        h[4 * g + 0] = (_Float16)(copysignf(fmaxf(m0 - t, 0.0f), v[0]) * scale);
        h[4 * g + 1] = (_Float16)(copysignf(fmaxf(m1 - t, 0.0f), v[1]) * scale);
        h[4 * g + 2] = (_Float16)(copysignf(fmaxf(m2 - t, 0.0f), v[2]) * scale);
        h[4 * g + 3] = (_Float16)(copysignf(fmaxf(m3 - t, 0.0f), v[3]) * scale);
    }
    return h;
}

// ---------------------------------------------------------------------------
__global__ __launch_bounds__(256) void prep_kernel(
    const float* __restrict__ w_in, const float* __restrict__ w_out,
    const float* __restrict__ s_in_p, const float* __restrict__ s_out_p,
    _Float16* __restrict__ sw_in, _Float16* __restrict__ sw_out)
{
    const int tid = blockIdx.x * 256 + threadIdx.x;
    const int HALF = RANK * IN_F / 8;
    const float* src; _Float16* dst; float sc; int g;
    if (tid < HALF) { src = w_in;  dst = sw_in;  sc = *s_in_p;  g = tid; }
    else            { src = w_out; dst = sw_out; sc = *s_out_p; g = tid - HALF; }
    half8 h = thresh8(src + (size_t)g * 8, sc);
    *(half8*)(dst + (size_t)g * 8) = h;
}

// ---------------------------------------------------------------------------
// k_p1x4: gemm1 (r11 k_p1 dataflow VERBATIM) repeated 4x internally.
// Idempotent: acc re-zeroed per rep, same xpw written per rep. The 4x makes
// this dispatch's duration exceed the harness fill rows -> counters visible.
// ---------------------------------------------------------------------------
__global__ __launch_bounds__(256) void k_p1x4(
    const float* __restrict__ x, const _Float16* __restrict__ sw_in,
    _Float16* __restrict__ xpw)
{
    __shared__ __align__(16) char smem[2 * 16 * KCHUNK * 2];
    __shared__ _Float16 xpl[16][RANK];
    auto xh = (_Float16 (*)[16][KCHUNK])smem;

    const int t    = threadIdx.x;
    const int wave = t >> 6;
    const int lane = t & 63;
    const int row  = lane & 15;
    const int kg   = lane >> 4;
    const int m0   = blockIdx.x * 16;
    const int sr   = t >> 7;
    const int skb  = t & 127;

    f32x4 ra[8], rb[8];
    auto issue = [&](int kc) {
        #pragma unroll
        for (int i = 0; i < 8; ++i) {
            const float* src = x + (size_t)(m0 + i * 2 + sr) * IN_F + kc + skb * 8;
            ra[i] = *(const f32x4*)src;
            rb[i] = *(const f32x4*)(src + 4);
        }
    };
    auto cstore = [&](int buf) {
        #pragma unroll
        for (int i = 0; i < 8; ++i) {
            const int r = i * 2 + sr;
            half8 h;
            #pragma unroll
            for (int j = 0; j < 4; ++j) {
                h[j]     = (_Float16)ra[i][j];
                h[j + 4] = (_Float16)rb[i][j];
            }
            *(half8*)&xh[buf][r][(skb ^ (r & 7)) << 3] = h;
        }
    };

    const _Float16* wr = sw_in + (size_t)(wave * 16 + row) * IN_F + kg * 8;

    #pragma unroll 1
    for (int rep = 0; rep < 4; ++rep) {
        f32x4 acc1 = {0.f, 0.f, 0.f, 0.f};

        issue(0);
        cstore(0);
        __syncthreads();
        int cur = 0;
        for (int kci = 0; kci < NKC; ++kci) {
            if (kci + 1 < NKC) issue((kci + 1) * KCHUNK);
            const int kc = kci * KCHUNK;
            #pragma unroll 4
            for (int k0 = 0; k0 < KCHUNK; k0 += 64) {
                const int kb = (k0 >> 3) + kg;
                half8 alo = *(const half8*)&xh[cur][row][(kb       ^ (row & 7)) << 3];
                half8 ahi = *(const half8*)&xh[cur][row][((kb + 4) ^ (row & 7)) << 3];
                half8 blo = *(const half8*)(wr + kc + k0);
                half8 bhi = *(const half8*)(wr + kc + k0 + 32);
                acc1 = __builtin_amdgcn_mfma_f32_16x16x32_f16(alo, blo, acc1, 0, 0, 0);
                acc1 = __builtin_amdgcn_mfma_f32_16x16x32_f16(ahi, bhi, acc1, 0, 0, 0);
            }
            if (kci + 1 < NKC) cstore(cur ^ 1);
            __syncthreads();
            cur ^= 1;
        }

        #pragma unroll
        for (int r = 0; r < 4; ++r)
            xpl[kg * 4 + r][wave * 16 + row] = (_Float16)acc1[r];
        __syncthreads();

        for (int i = t; i < 16 * RANK; i += 256)
            xpw[(size_t)blockIdx.x * 1024 + i] = xpl[i >> 6][i & 63];
        __syncthreads();   // xpl/xh safe to overwrite next rep
    }
}

// ---------------------------------------------------------------------------
// k_p2: gemm2 (r11/r12 VERBATIM, passed twice), writes final d_out.
// ---------------------------------------------------------------------------
__global__ __launch_bounds__(256) void k_p2(
    const _Float16* __restrict__ xpw, const _Float16* __restrict__ sw_out,
    const float* __restrict__ bias, float* __restrict__ out)
{
    __shared__ __align__(16) char smem[2 * 16 * KCHUNK * 2];
    __shared__ _Float16 xpl[16][RANK];

    const int t    = threadIdx.x;
    const int wave = t >> 6;
    const int lane = t & 63;
    const int row  = lane & 15;
    const int kg   = lane >> 4;
    const int m0   = blockIdx.x * 16;

    for (int i = t; i < 16 * RANK; i += 256)
        xpl[i >> 6][i & 63] = xpw[(size_t)blockIdx.x * 1024 + i];
    __syncthreads();

    const half8 a_lo = *(const half8*)&xpl[row][kg * 8];
    const half8 a_hi = *(const half8*)&xpl[row][kg * 8 + 32];
    const float scaling = 1.0f / 64.0f;

    float* tb = (float*)smem + wave * 2048;
    const int ncol0 = wave * 1024;

    for (int g = 0; g < 8; ++g) {
        const int gc = ncol0 + g * 128;
        #pragma unroll
        for (int c2 = 0; c2 < 2; ++c2) {
            const int cg = gc + c2 * 64;
            f32x4 acc[4] = {{0.f,0.f,0.f,0.f},{0.f,0.f,0.f,0.f},
                            {0.f,0.f,0.f,0.f},{0.f,0.f,0.f,0.f}};
            #pragma unroll
            for (int nt = 0; nt < 4; ++nt) {
                const _Float16* wp = sw_out + (size_t)(cg + nt * 16 + row) * RANK + kg * 8;
                half8 blo = *(const half8*)wp;
                half8 bhi = *(const half8*)(wp + 32);
                acc[nt] = __builtin_amdgcn_mfma_f32_16x16x32_f16(a_lo, blo, acc[nt], 0, 0, 0);
                acc[nt] = __builtin_amdgcn_mfma_f32_16x16x32_f16(a_hi, bhi, acc[nt], 0, 0, 0);
            }
            #pragma unroll
            for (int nt = 0; nt < 4; ++nt) {
                const float b = bias[cg + nt * 16 + row];
                #pragma unroll
                for (int r = 0; r < 4; ++r)
                    tb[(kg * 4 + r) * 128 + c2 * 64 + nt * 16 + row] =
                        (acc[nt][r] + b) * scaling;
            }
        }
        #pragma unroll
        for (int i = 0; i < 8; ++i) {
            const int s    = i * 64 + lane;
            const int orow = s >> 5;
            const int c4   = s & 31;
            f32x4 v = *(const f32x4*)&tb[orow * 128 + c4 * 4];
            *(f32x4*)&out[(size_t)(m0 + orow) * OUT_F + gc + c4 * 4] = v;
        }
    }
}

// ---------------------------------------------------------------------------
// Mid tier: r9 fused kernel (90.6 us) for ws in [1,2) MiB.
// ---------------------------------------------------------------------------
__global__ __launch_bounds__(256) void k_full(
    const float* __restrict__ x, const _Float16* __restrict__ sw_in,
    const _Float16* __restrict__ sw_out, const float* __restrict__ bias,
    float* __restrict__ out)
{
    __shared__ __align__(16) char smem[2 * 16 * KCHUNK * 2];
    __shared__ _Float16 xpl[16][RANK];
    auto xh = (_Float16 (*)[16][KCHUNK])smem;

    const int t    = threadIdx.x;
    const int wave = t >> 6;
    const int lane = t & 63;
    const int row  = lane & 15;
    const int kg   = lane >> 4;
    const int m0   = blockIdx.x * 16;
    const int sr   = t >> 7;
    const int skb  = t & 127;

    f32x4 ra[8], rb[8];
    auto issue = [&](int kc) {
        #pragma unroll
        for (int i = 0; i < 8; ++i) {
            const float* src = x + (size_t)(m0 + i * 2 + sr) * IN_F + kc + skb * 8;
            ra[i] = *(const f32x4*)src;
            rb[i] = *(const f32x4*)(src + 4);
        }
    };
    auto cstore = [&](int buf) {
        #pragma unroll
        for (int i = 0; i < 8; ++i) {
            const int r = i * 2 + sr;
            half8 h;
            #pragma unroll
            for (int j = 0; j < 4; ++j) {
                h[j]     = (_Float16)ra[i][j];
                h[j + 4] = (_Float16)rb[i][j];
            }
            *(half8*)&xh[buf][r][(skb ^ (r & 7)) << 3] = h;
        }
    };

    const _Float16* wr = sw_in + (size_t)(wave * 16 + row) * IN_F + kg * 8;
    f32x4 acc1 = {0.f, 0.f, 0.f, 0.f};

    issue(0);
    cstore(0);
    __syncthreads();
    int cur = 0;
    for (int kci = 0; kci < NKC; ++kci) {
        if (kci + 1 < NKC) issue((kci + 1) * KCHUNK);
        const int kc = kci * KCHUNK;
        #pragma unroll 4
        for (int k0 = 0; k0 < KCHUNK; k0 += 64) {
            const int kb = (k0 >> 3) + kg;
            half8 alo = *(const half8*)&xh[cur][row][(kb       ^ (row & 7)) << 3];
            half8 ahi = *(const half8*)&xh[cur][row][((kb + 4) ^ (row & 7)) << 3];
            half8 blo = *(const half8*)(wr + kc + k0);
            half8 bhi = *(const half8*)(wr + kc + k0 + 32);
            acc1 = __builtin_amdgcn_mfma_f32_16x16x32_f16(alo, blo, acc1, 0, 0, 0);
            acc1 = __builtin_amdgcn_mfma_f32_16x16x32_f16(ahi, bhi, acc1, 0, 0, 0);
        }
        if (kci + 1 < NKC) cstore(cur ^ 1);
        __syncthreads();
        cur ^= 1;
    }

    #pragma unroll
    for (int r = 0; r < 4; ++r)
        xpl[kg * 4 + r][wave * 16 + row] = (_Float16)acc1[r];
    __syncthreads();

    const half8 a_lo = *(const half8*)&xpl[row][kg * 8];
    const half8 a_hi = *(const half8*)&xpl[row][kg * 8 + 32];
    const float scaling = 1.0f / 64.0f;

    float* tb = (float*)smem + wave * 2048;
    const int ncol0 = wave * 1024;

    for (int g = 0; g < 8; ++g) {
        const int gc = ncol0 + g * 128;
        #pragma unroll
        for (int c2 = 0; c2 < 2; ++c2) {
            const int cg = gc + c2 * 64;
            f32x4 acc[4] = {{0.f,0.f,0.f,0.f},{0.f,0.f,0.f,0.f},
                            {0.f,0.f,0.f,0.f},{0.f,0.f,0.f,0.f}};
            #pragma unroll
            for (int nt = 0; nt < 4; ++nt) {
                const _Float16* wp = sw_out + (size_t)(cg + nt * 16 + row) * RANK + kg * 8;
                half8 blo = *(const half8*)wp;
                half8 bhi = *(const half8*)(wp + 32);
                acc[nt] = __builtin_amdgcn_mfma_f32_16x16x32_f16(a_lo, blo, acc[nt], 0, 0, 0);
                acc[nt] = __builtin_amdgcn_mfma_f32_16x16x32_f16(a_hi, bhi, acc[nt], 0, 0, 0);
            }
            #pragma unroll
            for (int nt = 0; nt < 4; ++nt) {
                const float b = bias[cg + nt * 16 + row];
                #pragma unroll
                for (int r = 0; r < 4; ++r)
                    tb[(kg * 4 + r) * 128 + c2 * 64 + nt * 16 + row] =
                        (acc[nt][r] + b) * scaling;
            }
        }
        #pragma unroll
        for (int i = 0; i < 8; ++i) {
            const int s    = i * 64 + lane;
            const int orow = s >> 5;
            const int c4   = s & 31;
            f32x4 v = *(const f32x4*)&tb[orow * 128 + c4 * 4];
            *(f32x4*)&out[(size_t)(m0 + orow) * OUT_F + gc + c4 * 4] = v;
        }
    }
}

// ---------------------------------------------------------------------------
// Fallback: round-5 kernel VERBATIM (155 us, no ws).
// ---------------------------------------------------------------------------
__global__ __launch_bounds__(256) void loro_fallback(
    const float* __restrict__ x, const float* __restrict__ w_in,
    const float* __restrict__ w_out, const float* __restrict__ bias,
    const float* __restrict__ s_in_p, const float* __restrict__ s_out_p,
    float* __restrict__ out)
{
    __shared__ _Float16 xh[16][KCHUNK];
    __shared__ _Float16 xpl[16][RANK];

    const int t    = threadIdx.x;
    const int wave = t >> 6;
    const int lane = t & 63;
    const int row  = lane & 15;
    const int kg   = lane >> 4;
    const int m0   = blockIdx.x * 16;
    const float s_in  = *s_in_p;
    const float s_out = *s_out_p;

    f32x4 acc1 = {0.f, 0.f, 0.f, 0.f};
    const float* wr = w_in + (size_t)(wave * 16 + row) * IN_F + kg * 8;

    for (int kc = 0; kc < IN_F; kc += KCHUNK) {
        __syncthreads();
        #pragma unroll
        for (int i = 0; i < 8; ++i) {
            const int f  = i * 2048 + t * 8;
            const int r  = f >> 10;
            const int cl = f & (KCHUNK - 1);
            const float* src = x + (size_t)(m0 + r) * IN_F + kc + cl;
            f32x4 a = *(const f32x4*)src;
            f32x4 b = *(const f32x4*)(src + 4);
            #pragma unroll
            for (int j = 0; j < 4; ++j) {
                xh[r][cl + j]     = (_Float16)a[j];
                xh[r][cl + 4 + j] = (_Float16)b[j];
            }
        }
        __syncthreads();

        #pragma unroll 4
        for (int k0 = 0; k0 < KCHUNK; k0 += 64) {
            half8 alo = *(const half8*)&xh[row][k0 + kg * 8];
            half8 ahi = *(const half8*)&xh[row][k0 + kg * 8 + 32];
            half8 blo = thresh8(wr + kc + k0,      s_in);
            half8 bhi = thresh8(wr + kc + k0 + 32, s_in);
            acc1 = __builtin_amdgcn_mfma_f32_16x16x32_f16(alo, blo, acc1, 0, 0, 0);
            acc1 = __builtin_amdgcn_mfma_f32_16x16x32_f16(ahi, bhi, acc1, 0, 0, 0);
        }
    }

    #pragma unroll
    for (int r = 0; r < 4; ++r)
        xpl[kg * 4 + r][wave * 16 + row] = (_Float16)acc1[r];
    __syncthreads();

    const half8 a_lo = *(const half8*)&xpl[row][kg * 8];
    const half8 a_hi = *(const half8*)&xpl[row][kg * 8 + 32];
    const float scaling = 1.0f / 64.0f;

    for (int c = 0; c < 16; ++c) {
        f32x4 acc[4] = {{0.f,0.f,0.f,0.f},{0.f,0.f,0.f,0.f},
                        {0.f,0.f,0.f,0.f},{0.f,0.f,0.f,0.f}};
        #pragma unroll
        for (int nt = 0; nt < 4; ++nt) {
            const float* wp = w_out
                + (size_t)(c * 256 + wave * 64 + nt * 16 + row) * RANK + kg * 8;
            half8 blo = thresh8(wp,      s_out);
            half8 bhi = thresh8(wp + 32, s_out);
            acc[nt] = __builtin_amdgcn_mfma_f32_16x16x32_f16(a_lo, blo, acc[nt], 0, 0, 0);
            acc[nt] = __builtin_amdgcn_mfma_f32_16x16x32_f16(a_hi, bhi, acc[nt], 0, 0, 0);
        }
        #pragma unroll
        for (int nt = 0; nt < 4; ++nt) {
            const int col = c * 256 + wave * 64 + nt * 16 + row;
            const float b = bias[col];
            #pragma unroll
            for (int r = 0; r < 4; ++r)
                out[(size_t)(m0 + kg * 4 + r) * OUT_F + col] = (acc[nt][r] + b) * scaling;
        }
    }
}

// ---------------------------------------------------------------------------
extern "C" void kernel_launch(void* const* d_in, const int* in_sizes, int n_in,
                              void* d_out, int out_size, void* d_ws, size_t ws_size,
                              hipStream_t stream) {
    (void)in_sizes; (void)n_in; (void)out_size;
    const float* x     = (const float*)d_in[0];
    const float* w_in  = (const float*)d_in[1];
    const float* w_out = (const float*)d_in[2];
    const float* bias  = (const float*)d_in[3];
    const float* s_in  = (const float*)d_in[4];
    const float* s_out = (const float*)d_in[5];
    float* out = (float*)d_out;

    const size_t need_sw = (size_t)(RANK * IN_F + OUT_F * RANK) * sizeof(_Float16); // 1 MiB
    const size_t need_ab = need_sw + (size_t)NBLK * 1024 * sizeof(_Float16);        // 2 MiB

    if (d_ws != nullptr && ws_size >= need_ab) {
        _Float16* sw_in  = (_Float16*)d_ws;
        _Float16* sw_out = sw_in + (size_t)RANK * IN_F;
        _Float16* xpw    = (_Float16*)((char*)d_ws + need_sw);

        prep_kernel<<<(RANK * IN_F + OUT_F * RANK) / 8 / 256, 256, 0, stream>>>(
            w_in, w_out, s_in, s_out, sw_in, sw_out);
        k_p1x4<<<NBLK, 256, 0, stream>>>(x, sw_in, xpw);          // 4x internal repeat
        k_p2  <<<NBLK, 256, 0, stream>>>(xpw, sw_out, bias, out); // final d_out
    } else if (d_ws != nullptr && ws_size >= need_sw) {
        _Float16* sw_in  = (_Float16*)d_ws;
        _Float16* sw_out = sw_in + (size_t)RANK * IN_F;
        prep_kernel<<<(RANK * IN_F + OUT_F * RANK) / 8 / 256, 256, 0, stream>>>(
            w_in, w_out, s_in, s_out, sw_in, sw_out);
        k_full<<<NBLK, 256, 0, stream>>>(x, sw_in, sw_out, bias, out);
    } else {
        loro_fallback<<<M_TOT / 16, 256, 0, stream>>>(
            x, w_in, w_out, bias, s_in, s_out, out);
    }
}

// Round 14
// 93.125 us; speedup vs baseline: 1.9504x; 1.9504x over previous
//
#include <hip/hip_runtime.h>

typedef _Float16 half8 __attribute__((ext_vector_type(8)));
typedef float f32x4 __attribute__((ext_vector_type(4)));

#define IN_F 4096
#define OUT_F 4096
#define RANK 64
#define M_TOT 8192
#define KCHUNK 1024
#define NKC (IN_F / KCHUNK)
#define NBLK (M_TOT / 16)   // 512

// 2 aligned groups of 4: 2:4 soft-threshold, scale, cast f16. VALIDATED (r4/r5).
__device__ __forceinline__ half8 thresh8(const float* __restrict__ p, float scale) {
    half8 h;
    #pragma unroll
    for (int g = 0; g < 2; ++g) {
        f32x4 v = *(const f32x4*)(p + 4 * g);
        float m0 = fabsf(v[0]), m1 = fabsf(v[1]), m2 = fabsf(v[2]), m3 = fabsf(v[3]);
        float lo1 = fminf(m0, m1), hi1 = fmaxf(m0, m1);
        float lo2 = fminf(m2, m3), hi2 = fmaxf(m2, m3);
        float t = fminf(fmaxf(lo1, lo2), fminf(hi1, hi2));
        h[4 * g + 0] = (_Float16)(copysignf(fmaxf(m0 - t, 0.0f), v[0]) * scale);
        h[4 * g + 1] = (_Float16)(copysignf(fmaxf(m1 - t, 0.0f), v[1]) * scale);
        h[4 * g + 2] = (_Float16)(copysignf(fmaxf(m2 - t, 0.0f), v[2]) * scale);
        h[4 * g + 3] = (_Float16)(copysignf(fmaxf(m3 - t, 0.0f), v[3]) * scale);
    }
    return h;
}

// ---------------------------------------------------------------------------
__global__ __launch_bounds__(256) void prep_kernel(
    const float* __restrict__ w_in, const float* __restrict__ w_out,
    const float* __restrict__ s_in_p, const float* __restrict__ s_out_p,
    _Float16* __restrict__ sw_in, _Float16* __restrict__ sw_out)
{
    const int tid = blockIdx.x * 256 + threadIdx.x;
    const int HALF = RANK * IN_F / 8;
    const float* src; _Float16* dst; float sc; int g;
    if (tid < HALF) { src = w_in;  dst = sw_in;  sc = *s_in_p;  g = tid; }
    else            { src = w_out; dst = sw_out; sc = *s_out_p; g = tid - HALF; }
    half8 h = thresh8(src + (size_t)g * 8, sc);
    *(half8*)(dst + (size_t)g * 8) = h;
}

// ---------------------------------------------------------------------------
// k_p1ks: gemm1 with 2-way K-split. Grid = 512 M-tiles x 2 K-halves = 1024
// (4 blocks/CU). Each block: 2 serial K-chunks (r13's p1 had 4 -> halved
// serial latency). Dataflow = r13 k_p1 VERBATIM except kbase offset and the
// epilogue: each wave writes its f32 acc directly to xppw (waves own
// disjoint cols -> no intra-block reduce).
// MFMA 16x16x32_f16: A/B lane l elem j -> (free = l&15, k = (l>>4)*8 + j);
// D lane l reg r -> (Afree = (l>>4)*4 + r, Bfree = l&15).
// ---------------------------------------------------------------------------
__global__ __launch_bounds__(256) void k_p1ks(
    const float* __restrict__ x, const _Float16* __restrict__ sw_in,
    float* __restrict__ xppw)
{
    __shared__ __align__(16) char smem[2 * 16 * KCHUNK * 2];   // 64 KiB dbuf
    auto xh = (_Float16 (*)[16][KCHUNK])smem;

    const int t    = threadIdx.x;
    const int wave = t >> 6;
    const int lane = t & 63;
    const int row  = lane & 15;
    const int kg   = lane >> 4;
    const int mt   = blockIdx.x >> 1;
    const int ks   = blockIdx.x & 1;
    const int m0   = mt * 16;
    const int kbase = ks * (IN_F / 2);   // 0 or 2048
    const int sr   = t >> 7;
    const int skb  = t & 127;

    f32x4 ra[8], rb[8];
    auto issue = [&](int kc) {
        #pragma unroll
        for (int i = 0; i < 8; ++i) {
            const float* src = x + (size_t)(m0 + i * 2 + sr) * IN_F + kc + skb * 8;
            ra[i] = *(const f32x4*)src;
            rb[i] = *(const f32x4*)(src + 4);
        }
    };
    auto cstore = [&](int buf) {
        #pragma unroll
        for (int i = 0; i < 8; ++i) {
            const int r = i * 2 + sr;
            half8 h;
            #pragma unroll
            for (int j = 0; j < 4; ++j) {
                h[j]     = (_Float16)ra[i][j];
                h[j + 4] = (_Float16)rb[i][j];
            }
            *(half8*)&xh[buf][r][(skb ^ (r & 7)) << 3] = h;
        }
    };

    const _Float16* wr = sw_in + (size_t)(wave * 16 + row) * IN_F + kg * 8;
    f32x4 acc1 = {0.f, 0.f, 0.f, 0.f};

    issue(kbase);
    cstore(0);
    __syncthreads();
    int cur = 0;
    #pragma unroll 1
    for (int kci = 0; kci < 2; ++kci) {
        if (kci == 0) issue(kbase + KCHUNK);
        const int kc = kbase + kci * KCHUNK;
        #pragma unroll 4
        for (int k0 = 0; k0 < KCHUNK; k0 += 64) {
            const int kb = (k0 >> 3) + kg;
            half8 alo = *(const half8*)&xh[cur][row][(kb       ^ (row & 7)) << 3];
            half8 ahi = *(const half8*)&xh[cur][row][((kb + 4) ^ (row & 7)) << 3];
            half8 blo = *(const half8*)(wr + kc + k0);
            half8 bhi = *(const half8*)(wr + kc + k0 + 32);
            acc1 = __builtin_amdgcn_mfma_f32_16x16x32_f16(alo, blo, acc1, 0, 0, 0);
            acc1 = __builtin_amdgcn_mfma_f32_16x16x32_f16(ahi, bhi, acc1, 0, 0, 0);
        }
        if (kci == 0) cstore(cur ^ 1);
        __syncthreads();
        cur ^= 1;
    }

    // D layout: m-local = kg*4+r, col = wave*16 + row. f32 partial per K-half.
    #pragma unroll
    for (int r = 0; r < 4; ++r)
        xppw[((size_t)ks * M_TOT + m0 + kg * 4 + r) * RANK + wave * 16 + row] = acc1[r];
}

// ---------------------------------------------------------------------------
// k_p2: gemm2 (r11-r13 VERBATIM except xp source = fixed-order sum of the
// two f32 K-partials, then f16 cast). Writes final d_out. grid 512 x 256.
// ---------------------------------------------------------------------------
__global__ __launch_bounds__(256) void k_p2(
    const float* __restrict__ xppw, const _Float16* __restrict__ sw_out,
    const float* __restrict__ bias, float* __restrict__ out)
{
    __shared__ __align__(16) char smem[2 * 16 * KCHUNK * 2];
    __shared__ _Float16 xpl[16][RANK];

    const int t    = threadIdx.x;
    const int wave = t >> 6;
    const int lane = t & 63;
    const int row  = lane & 15;
    const int kg   = lane >> 4;
    const int m0   = blockIdx.x * 16;

    for (int i = t; i < 16 * RANK; i += 256) {
        const int m = i >> 6, n = i & 63;
        const size_t base = (size_t)(m0 + m) * RANK + n;
        const size_t S = (size_t)M_TOT * RANK;
        xpl[m][n] = (_Float16)(xppw[base] + xppw[S + base]);   // fixed order
    }
    __syncthreads();

    const half8 a_lo = *(const half8*)&xpl[row][kg * 8];
    const half8 a_hi = *(const half8*)&xpl[row][kg * 8 + 32];
    const float scaling = 1.0f / 64.0f;

    float* tb = (float*)smem + wave * 2048;
    const int ncol0 = wave * 1024;

    for (int g = 0; g < 8; ++g) {
        const int gc = ncol0 + g * 128;
        #pragma unroll
        for (int c2 = 0; c2 < 2; ++c2) {
            const int cg = gc + c2 * 64;
            f32x4 acc[4] = {{0.f,0.f,0.f,0.f},{0.f,0.f,0.f,0.f},
                            {0.f,0.f,0.f,0.f},{0.f,0.f,0.f,0.f}};
            #pragma unroll
            for (int nt = 0; nt < 4; ++nt) {
                const _Float16* wp = sw_out + (size_t)(cg + nt * 16 + row) * RANK + kg * 8;
                half8 blo = *(const half8*)wp;
                half8 bhi = *(const half8*)(wp + 32);
                acc[nt] = __builtin_amdgcn_mfma_f32_16x16x32_f16(a_lo, blo, acc[nt], 0, 0, 0);
                acc[nt] = __builtin_amdgcn_mfma_f32_16x16x32_f16(a_hi, bhi, acc[nt], 0, 0, 0);
            }
            #pragma unroll
            for (int nt = 0; nt < 4; ++nt) {
                const float b = bias[cg + nt * 16 + row];
                #pragma unroll
                for (int r = 0; r < 4; ++r)
                    tb[(kg * 4 + r) * 128 + c2 * 64 + nt * 16 + row] =
                        (acc[nt][r] + b) * scaling;
            }
        }
        #pragma unroll
        for (int i = 0; i < 8; ++i) {
            const int s    = i * 64 + lane;
            const int orow = s >> 5;
            const int c4   = s & 31;
            f32x4 v = *(const f32x4*)&tb[orow * 128 + c4 * 4];
            *(f32x4*)&out[(size_t)(m0 + orow) * OUT_F + gc + c4 * 4] = v;
        }
    }
}

// ---------------------------------------------------------------------------
// Mid tier: r9 fused kernel (90.6 us) for ws in [1,5) MiB.
// ---------------------------------------------------------------------------
__global__ __launch_bounds__(256) void k_full(
    const float* __restrict__ x, const _Float16* __restrict__ sw_in,
    const _Float16* __restrict__ sw_out, const float* __restrict__ bias,
    float* __restrict__ out)
{
    __shared__ __align__(16) char smem[2 * 16 * KCHUNK * 2];
    __shared__ _Float16 xpl[16][RANK];
    auto xh = (_Float16 (*)[16][KCHUNK])smem;

    const int t    = threadIdx.x;
    const int wave = t >> 6;
    const int lane = t & 63;
    const int row  = lane & 15;
    const int kg   = lane >> 4;
    const int m0   = blockIdx.x * 16;
    const int sr   = t >> 7;
    const int skb  = t & 127;

    f32x4 ra[8], rb[8];
    auto issue = [&](int kc) {
        #pragma unroll
        for (int i = 0; i < 8; ++i) {
            const float* src = x + (size_t)(m0 + i * 2 + sr) * IN_F + kc + skb * 8;
            ra[i] = *(const f32x4*)src;
            rb[i] = *(const f32x4*)(src + 4);
        }
    };
    auto cstore = [&](int buf) {
        #pragma unroll
        for (int i = 0; i < 8; ++i) {
            const int r = i * 2 + sr;
            half8 h;
            #pragma unroll
            for (int j = 0; j < 4; ++j) {
                h[j]     = (_Float16)ra[i][j];
                h[j + 4] = (_Float16)rb[i][j];
            }
            *(half8*)&xh[buf][r][(skb ^ (r & 7)) << 3] = h;
        }
    };

    const _Float16* wr = sw_in + (size_t)(wave * 16 + row) * IN_F + kg * 8;
    f32x4 acc1 = {0.f, 0.f, 0.f, 0.f};

    issue(0);
    cstore(0);
    __syncthreads();
    int cur = 0;
    for (int kci = 0; kci < NKC; ++kci) {
        if (kci + 1 < NKC) issue((kci + 1) * KCHUNK);
        const int kc = kci * KCHUNK;
        #pragma unroll 4
        for (int k0 = 0; k0 < KCHUNK; k0 += 64) {
            const int kb = (k0 >> 3) + kg;
            half8 alo = *(const half8*)&xh[cur][row][(kb       ^ (row & 7)) << 3];
            half8 ahi = *(const half8*)&xh[cur][row][((kb + 4) ^ (row & 7)) << 3];
            half8 blo = *(const half8*)(wr + kc + k0);
            half8 bhi = *(const half8*)(wr + kc + k0 + 32);
            acc1 = __builtin_amdgcn_mfma_f32_16x16x32_f16(alo, blo, acc1, 0, 0, 0);
            acc1 = __builtin_amdgcn_mfma_f32_16x16x32_f16(ahi, bhi, acc1, 0, 0, 0);
        }
        if (kci + 1 < NKC) cstore(cur ^ 1);
        __syncthreads();
        cur ^= 1;
    }

    #pragma unroll
    for (int r = 0; r < 4; ++r)
        xpl[kg * 4 + r][wave * 16 + row] = (_Float16)acc1[r];
    __syncthreads();

    const half8 a_lo = *(const half8*)&xpl[row][kg * 8];
    const half8 a_hi = *(const half8*)&xpl[row][kg * 8 + 32];
    const float scaling = 1.0f / 64.0f;

    float* tb = (float*)smem + wave * 2048;
    const int ncol0 = wave * 1024;

    for (int g = 0; g < 8; ++g) {
        const int gc = ncol0 + g * 128;
        #pragma unroll
        for (int c2 = 0; c2 < 2; ++c2) {
            const int cg = gc + c2 * 64;
            f32x4 acc[4] = {{0.f,0.f,0.f,0.f},{0.f,0.f,0.f,0.f},
                            {0.f,0.f,0.f,0.f},{0.f,0.f,0.f,0.f}};
            #pragma unroll
            for (int nt = 0; nt < 4; ++nt) {
                const _Float16* wp = sw_out + (size_t)(cg + nt * 16 + row) * RANK + kg * 8;
                half8 blo = *(const half8*)wp;
                half8 bhi = *(const half8*)(wp + 32);
                acc[nt] = __builtin_amdgcn_mfma_f32_16x16x32_f16(a_lo, blo, acc[nt], 0, 0, 0);
                acc[nt] = __builtin_amdgcn_mfma_f32_16x16x32_f16(a_hi, bhi, acc[nt], 0, 0, 0);
            }
            #pragma unroll
            for (int nt = 0; nt < 4; ++nt) {
                const float b = bias[cg + nt * 16 + row];
                #pragma unroll
                for (int r = 0; r < 4; ++r)
                    tb[(kg * 4 + r) * 128 + c2 * 64 + nt * 16 + row] =
                        (acc[nt][r] + b) * scaling;
            }
        }
        #pragma unroll
        for (int i = 0; i < 8; ++i) {
            const int s    = i * 64 + lane;
            const int orow = s >> 5;
            const int c4   = s & 31;
            f32x4 v = *(const f32x4*)&tb[orow * 128 + c4 * 4];
            *(f32x4*)&out[(size_t)(m0 + orow) * OUT_F + gc + c4 * 4] = v;
        }
    }
}

// ---------------------------------------------------------------------------
// Fallback: round-5 kernel VERBATIM (155 us, no ws).
// ---------------------------------------------------------------------------
__global__ __launch_bounds__(256) void loro_fallback(
    const float* __restrict__ x, const float* __restrict__ w_in,
    const float* __restrict__ w_out, const float* __restrict__ bias,
    const float* __restrict__ s_in_p, const float* __restrict__ s_out_p,
    float* __restrict__ out)
{
    __shared__ _Float16 xh[16][KCHUNK];
    __shared__ _Float16 xpl[16][RANK];

    const int t    = threadIdx.x;
    const int wave = t >> 6;
    const int lane = t & 63;
    const int row  = lane & 15;
    const int kg   = lane >> 4;
    const int m0   = blockIdx.x * 16;
    const float s_in  = *s_in_p;
    const float s_out = *s_out_p;

    f32x4 acc1 = {0.f, 0.f, 0.f, 0.f};
    const float* wr = w_in + (size_t)(wave * 16 + row) * IN_F + kg * 8;

    for (int kc = 0; kc < IN_F; kc += KCHUNK) {
        __syncthreads();
        #pragma unroll
        for (int i = 0; i < 8; ++i) {
            const int f  = i * 2048 + t * 8;
            const int r  = f >> 10;
            const int cl = f & (KCHUNK - 1);
            const float* src = x + (size_t)(m0 + r) * IN_F + kc + cl;
            f32x4 a = *(const f32x4*)src;
            f32x4 b = *(const f32x4*)(src + 4);
            #pragma unroll
            for (int j = 0; j < 4; ++j) {
                xh[r][cl + j]     = (_Float16)a[j];
                xh[r][cl + 4 + j] = (_Float16)b[j];
            }
        }
        __syncthreads();

        #pragma unroll 4
        for (int k0 = 0; k0 < KCHUNK; k0 += 64) {
            half8 alo = *(const half8*)&xh[row][k0 + kg * 8];
            half8 ahi = *(const half8*)&xh[row][k0 + kg * 8 + 32];
            half8 blo = thresh8(wr + kc + k0,      s_in);
            half8 bhi = thresh8(wr + kc + k0 + 32, s_in);
            acc1 = __builtin_amdgcn_mfma_f32_16x16x32_f16(alo, blo, acc1, 0, 0, 0);
            acc1 = __builtin_amdgcn_mfma_f32_16x16x32_f16(ahi, bhi, acc1, 0, 0, 0);
        }
    }

    #pragma unroll
    for (int r = 0; r < 4; ++r)
        xpl[kg * 4 + r][wave * 16 + row] = (_Float16)acc1[r];
    __syncthreads();

    const half8 a_lo = *(const half8*)&xpl[row][kg * 8];
    const half8 a_hi = *(const half8*)&xpl[row][kg * 8 + 32];
    const float scaling = 1.0f / 64.0f;

    for (int c = 0; c < 16; ++c) {
        f32x4 acc[4] = {{0.f,0.f,0.f,0.f},{0.f,0.f,0.f,0.f},
                        {0.f,0.f,0.f,0.f},{0.f,0.f,0.f,0.f}};
        #pragma unroll
        for (int nt = 0; nt < 4; ++nt) {
            const float* wp = w_out
                + (size_t)(c * 256 + wave * 64 + nt * 16 + row) * RANK + kg * 8;
            half8 blo = thresh8(wp,      s_out);
            half8 bhi = thresh8(wp + 32, s_out);
            acc[nt] = __builtin_amdgcn_mfma_f32_16x16x32_f16(a_lo, blo, acc[nt], 0, 0, 0);
            acc[nt] = __builtin_amdgcn_mfma_f32_16x16x32_f16(a_hi, bhi, acc[nt], 0, 0, 0);
        }
        #pragma unroll
        for (int nt = 0; nt < 4; ++nt) {
            const int col = c * 256 + wave * 64 + nt * 16 + row;
            const float b = bias[col];
            #pragma unroll
            for (int r = 0; r < 4; ++r)
                out[(size_t)(m0 + kg * 4 + r) * OUT_F + col] = (acc[nt][r] + b) * scaling;
        }
    }
}

// ---------------------------------------------------------------------------
extern "C" void kernel_launch(void* const* d_in, const int* in_sizes, int n_in,
                              void* d_out, int out_size, void* d_ws, size_t ws_size,
                              hipStream_t stream) {
    (void)in_sizes; (void)n_in; (void)out_size;
    const float* x     = (const float*)d_in[0];
    const float* w_in  = (const float*)d_in[1];
    const float* w_out = (const float*)d_in[2];
    const float* bias  = (const float*)d_in[3];
    const float* s_in  = (const float*)d_in[4];
    const float* s_out = (const float*)d_in[5];
    float* out = (float*)d_out;

    const size_t need_sw   = (size_t)(RANK * IN_F + OUT_F * RANK) * sizeof(_Float16); // 1 MiB
    const size_t need_full = need_sw + 2 * (size_t)M_TOT * RANK * sizeof(float);      // 5 MiB

    if (d_ws != nullptr && ws_size >= need_full) {
        _Float16* sw_in  = (_Float16*)d_ws;
        _Float16* sw_out = sw_in + (size_t)RANK * IN_F;
        float*    xppw   = (float*)((char*)d_ws + need_sw);

        prep_kernel<<<(RANK * IN_F + OUT_F * RANK) / 8 / 256, 256, 0, stream>>>(
            w_in, w_out, s_in, s_out, sw_in, sw_out);
        k_p1ks<<<NBLK * 2, 256, 0, stream>>>(x, sw_in, xppw);
        k_p2  <<<NBLK, 256, 0, stream>>>(xppw, sw_out, bias, out);
    } else if (d_ws != nullptr && ws_size >= need_sw) {
        _Float16* sw_in  = (_Float16*)d_ws;
        _Float16* sw_out = sw_in + (size_t)RANK * IN_F;
        prep_kernel<<<(RANK * IN_F + OUT_F * RANK) / 8 / 256, 256, 0, stream>>>(
            w_in, w_out, s_in, s_out, sw_in, sw_out);
        k_full<<<NBLK, 256, 0, stream>>>(x, sw_in, sw_out, bias, out);
    } else {
        loro_fallback<<<M_TOT / 16, 256, 0, stream>>>(
            x, w_in, w_out, bias, s_in, s_out, out);
    }
}